// Round 1
// baseline (415.281 us; speedup 1.0000x reference)
//
#include <hip/hip_runtime.h>
#include <hip/hip_bf16.h>

// Dequant: out[r][c] = (float)q[r][c] * row_stats[r] * (1/127)
// ROWS=COLS=8192. Memory-bound streaming kernel.
// Each thread: one int4 load (16B) -> one float4 store (16B).
// 256-thread block covers 1024 contiguous elements = 1/8 of a row,
// so the row index (and scale) is block-uniform -> SGPR scale.

#define COLS 8192
#define INV127 (1.0f / 127.0f)

__global__ __launch_bounds__(256) void
bnb_dequant_kernel(const int4* __restrict__ q,
                   const float* __restrict__ stats,
                   float4* __restrict__ out,
                   int n4) {
    int idx = blockIdx.x * blockDim.x + threadIdx.x;
    if (idx >= n4) return;

    // 4 elements per thread, 256 threads per block -> 1024 elems/block,
    // 8 blocks per row of 8192.
    int row = blockIdx.x >> 3;              // block-uniform -> scalar
    float scale = stats[row] * INV127;      // compiler: s_load + s_mul

    int4 v = q[idx];
    float4 o;
    o.x = (float)v.x * scale;
    o.y = (float)v.y * scale;
    o.z = (float)v.z * scale;
    o.w = (float)v.w * scale;
    out[idx] = o;
}

extern "C" void kernel_launch(void* const* d_in, const int* in_sizes, int n_in,
                              void* d_out, int out_size, void* d_ws, size_t ws_size,
                              hipStream_t stream) {
    const int4*  q     = (const int4*)d_in[0];
    const float* stats = (const float*)d_in[1];
    float4*      out   = (float4*)d_out;

    int n4 = out_size / 4;                  // 16,777,216 int4-groups
    int block = 256;
    int grid = (n4 + block - 1) / block;    // 65,536 blocks

    bnb_dequant_kernel<<<grid, block, 0, stream>>>(q, stats, out, n4);
}